// Round 1
// baseline (366.015 us; speedup 1.0000x reference)
//
#include <hip/hip_runtime.h>

typedef unsigned int u32;
typedef unsigned short u16;
typedef __attribute__((ext_vector_type(8))) short short8;
typedef __attribute__((ext_vector_type(4))) float f4;

#define MFMA(a, b, c) __builtin_amdgcn_mfma_f32_16x16x32_bf16((a), (b), (c), 0, 0, 0)
#define LL 384
#define NPAIR 147456

// ---- helpers ----
__device__ __forceinline__ u16 f2bf(float f) {
    u32 u = __float_as_uint(f);
    u = (u + 0x7fffu + ((u >> 16) & 1u)) >> 16;
    return (u16)u;
}
__device__ __forceinline__ u32 pack2(float a, float b) {
    u32 ua = __float_as_uint(a); ua = (ua + 0x7fffu + ((ua >> 16) & 1u)) >> 16;
    u32 ub = __float_as_uint(b); ub = (ub + 0x7fffu + ((ub >> 16) & 1u)) >> 16;
    return ua | (ub << 16);
}
__device__ __forceinline__ short8 ld8(const u16* p) { return *reinterpret_cast<const short8*>(p); }

// 16-lane sum on the VALU pipe (DPP) instead of ds_swizzle (DS pipe).
// Groups are lane[16g..16g+15] == one DPP row. quad_perm xor1/xor2 give quad
// sums; row_ror:4 / row_ror:8 rotate whole quads within the row -> full sum in
// every lane of the row.
template <int CTRL>
__device__ __forceinline__ float dpp_add(float v) {
    int t = __builtin_amdgcn_update_dpp(0, __float_as_int(v), CTRL, 0xf, 0xf, true);
    return v + __int_as_float(t);
}
__device__ __forceinline__ float red16(float v) {
    v = dpp_add<0xB1>(v);    // quad_perm [1,0,3,2]  (xor 1)
    v = dpp_add<0x4E>(v);    // quad_perm [2,3,0,1]  (xor 2)
    v = dpp_add<0x124>(v);   // row_ror:4
    v = dpp_add<0x128>(v);   // row_ror:8
    return v;
}

// ---- workspace layout ----
// u16 region: [0,8192) WqSW  [8192,12288) WkSW  [12288,16384) WvSW  [16384,24576) WoSW
// float region (float idx): [12288..] GQ BQ GK BK GV BV (64 each), bo at 12672 (128)
// swizzle: sw[(k>>3)*N*8 + n*8 + (k&7)] = W'[k][n]

__global__ void prep_w(const float* __restrict__ Wq, const float* __restrict__ Wk,
                       const float* __restrict__ Wv, const float* __restrict__ Wo,
                       const float* __restrict__ zg, const float* __restrict__ tg,
                       float* __restrict__ ws) {
    int idx = blockIdx.x * blockDim.x + threadIdx.x;
    u16* wsu = (u16*)ws;
    if (idx < 8192) {               // WqSW, N=64, K=128, fold zg
        int kb = idx >> 9, rem = idx & 511, n = rem >> 3, j = rem & 7, k = kb * 8 + j;
        wsu[idx] = f2bf(Wq[k * 64 + n] * zg[k]);
    } else if (idx < 12288) {       // WkSW, N=64, K=64, fold tg
        int e = idx - 8192;
        int kb = e >> 9, rem = e & 511, n = rem >> 3, j = rem & 7, k = kb * 8 + j;
        wsu[idx] = f2bf(Wk[k * 64 + n] * tg[k]);
    } else if (idx < 16384) {       // WvSW
        int e = idx - 12288;
        int kb = e >> 9, rem = e & 511, n = rem >> 3, j = rem & 7, k = kb * 8 + j;
        wsu[idx] = f2bf(Wv[k * 64 + n] * tg[k]);
    } else if (idx < 24576) {       // WoSW, N=128, K=64, no fold
        int e = idx - 16384;
        int kb = e >> 10, rem = e & 1023, n = rem >> 3, j = rem & 7, k = kb * 8 + j;
        wsu[idx] = f2bf(Wo[k * 128 + n]);
    }
}

__global__ void prep_aux(const float* __restrict__ Wq, const float* __restrict__ Wk,
                         const float* __restrict__ Wv, const float* __restrict__ zg,
                         const float* __restrict__ zb, const float* __restrict__ tg,
                         const float* __restrict__ tb, const float* __restrict__ bo,
                         float* __restrict__ ws) {
    int idx = blockIdx.x * blockDim.x + threadIdx.x;
    if (idx < 384) {
        int g = idx >> 6, hc = idx & 63;
        float acc = 0.f;
        if (g == 0)      { for (int d = 0; d < 128; ++d) acc += zg[d] * Wq[d*64+hc]; ws[12288+hc] = acc; }
        else if (g == 1) { for (int d = 0; d < 128; ++d) acc += zb[d] * Wq[d*64+hc]; ws[12352+hc] = acc; }
        else if (g == 2) { for (int d = 0; d < 64;  ++d) acc += tg[d] * Wk[d*64+hc]; ws[12416+hc] = acc; }
        else if (g == 3) { for (int d = 0; d < 64;  ++d) acc += tb[d] * Wk[d*64+hc]; ws[12480+hc] = acc; }
        else if (g == 4) { for (int d = 0; d < 64;  ++d) acc += tg[d] * Wv[d*64+hc]; ws[12544+hc] = acc; }
        else             { for (int d = 0; d < 64;  ++d) acc += tb[d] * Wv[d*64+hc]; ws[12608+hc] = acc; }
    } else if (idx < 512) {
        ws[12672 + idx - 384] = bo[idx - 384];
    }
}

// block = 256 threads (4 waves), M = 32 pairs/block, grid = 4608
// LDS ~31 KB -> 5 blocks/CU (was 47.6 KB -> 3). Weights read direct from L2.
__global__ __launch_bounds__(256, 5) void tpa_main(
    const float* __restrict__ tmpl,   // [4][147456][64]
    const float* __restrict__ z,      // [147456][128]
    const float* __restrict__ mask,   // [4][384]
    const float* __restrict__ ws,
    float* __restrict__ out)          // [147456][128]
{
    __shared__ __align__(16) u16 sT[4 * 32 * 72];   // t bf16, stride 72
    __shared__ __align__(16) u16 sZ[32 * 136];      // z bf16 stride 136; later o bf16 stride 72
    __shared__ float sZr[32], sZrm[32];
    __shared__ float sTr[4 * 32], sTrm[4 * 32];
    __shared__ float sAux[384];                     // GQ BQ GK BK GV BV
    __shared__ float sBo[128];
    __shared__ float sPm[4 * 32];

    const int tid = threadIdx.x;
    const int p0 = blockIdx.x * 32;
    const u16* wsu = (const u16*)ws;

    // ================= phase 0: stage z/t tiles + aux =================
    if (tid < 128) {
        sAux[tid]       = ws[12288 + tid];
        sAux[128 + tid] = ws[12416 + tid];
        sAux[256 + tid] = ws[12544 + tid];
        sBo[tid]        = ws[12672 + tid];
        int tt = tid >> 5, rr = tid & 31;
        int p = p0 + rr, i = p / LL, j = p - i * LL;
        sPm[tt * 32 + rr] = mask[tt * LL + i] * mask[tt * LL + j];
    }
    {   // z tile: [32][128] f32, 8 threads/row
        int pp = tid >> 3, part = tid & 7;
        const float4* zg4 = (const float4*)(z + (size_t)(p0 + pp) * 128) + part * 4;
        float4 a0 = zg4[0], a1 = zg4[1], a2 = zg4[2], a3 = zg4[3];
        float s = a0.x+a0.y+a0.z+a0.w + a1.x+a1.y+a1.z+a1.w
                + a2.x+a2.y+a2.z+a2.w + a3.x+a3.y+a3.z+a3.w;
        float ss = a0.x*a0.x+a0.y*a0.y+a0.z*a0.z+a0.w*a0.w
                 + a1.x*a1.x+a1.y*a1.y+a1.z*a1.z+a1.w*a1.w
                 + a2.x*a2.x+a2.y*a2.y+a2.z*a2.z+a2.w*a2.w
                 + a3.x*a3.x+a3.y*a3.y+a3.z*a3.z+a3.w*a3.w;
        s += __shfl_xor(s, 1); ss += __shfl_xor(ss, 1);
        s += __shfl_xor(s, 2); ss += __shfl_xor(ss, 2);
        s += __shfl_xor(s, 4); ss += __shfl_xor(ss, 4);
        if (part == 0) {
            float mu = s * (1.f / 128.f);
            float var = fmaf(-mu, mu, ss * (1.f / 128.f));
            float r = rsqrtf(var + 1e-5f);
            sZr[pp] = r; sZrm[pp] = r * mu;
        }
        uint4 w0, w1;
        w0.x = pack2(a0.x, a0.y); w0.y = pack2(a0.z, a0.w);
        w0.z = pack2(a1.x, a1.y); w0.w = pack2(a1.z, a1.w);
        w1.x = pack2(a2.x, a2.y); w1.y = pack2(a2.z, a2.w);
        w1.z = pack2(a3.x, a3.y); w1.w = pack2(a3.z, a3.w);
        uint4* d = (uint4*)(sZ + pp * 136 + part * 16);
        d[0] = w0; d[1] = w1;
    }
    {   // t tiles: [4][32][64] f32, 2 threads/row
        int tt = tid >> 6, pp = (tid >> 1) & 31, part = tid & 1;
        const float4* tg4 = (const float4*)(tmpl + ((size_t)tt * NPAIR + p0 + pp) * 64) + part * 8;
        float s = 0.f, ss = 0.f;
        uint4 wbuf[4];
        #pragma unroll
        for (int c = 0; c < 4; ++c) {
            float4 b0 = tg4[c * 2], b1 = tg4[c * 2 + 1];
            s  += b0.x+b0.y+b0.z+b0.w + b1.x+b1.y+b1.z+b1.w;
            ss += b0.x*b0.x+b0.y*b0.y+b0.z*b0.z+b0.w*b0.w
                + b1.x*b1.x+b1.y*b1.y+b1.z*b1.z+b1.w*b1.w;
            wbuf[c].x = pack2(b0.x, b0.y); wbuf[c].y = pack2(b0.z, b0.w);
            wbuf[c].z = pack2(b1.x, b1.y); wbuf[c].w = pack2(b1.z, b1.w);
        }
        s += __shfl_xor(s, 1); ss += __shfl_xor(ss, 1);
        if (part == 0) {
            float mu = s * (1.f / 64.f);
            float var = fmaf(-mu, mu, ss * (1.f / 64.f));
            float r = rsqrtf(var + 1e-5f);
            sTr[tt * 32 + pp] = r; sTrm[tt * 32 + pp] = r * mu;
        }
        uint4* d = (uint4*)(sT + tt * 2304 + pp * 72 + part * 32);
        d[0] = wbuf[0]; d[1] = wbuf[1]; d[2] = wbuf[2]; d[3] = wbuf[3];
    }
    __syncthreads();

    // wave partition: rt = row-tile (16 rows), nh = n-half (2 head-tiles)
    const int wave = tid >> 6, lane = tid & 63, g = lane >> 4, l15 = lane & 15;
    const int rt = wave & 1, nh = wave >> 1;
    const int rowA = rt * 16 + l15;
    const int col0 = (2 * nh) * 16 + l15, col1 = (2 * nh + 1) * 16 + l15;
    int rowC[4];
    #pragma unroll
    for (int r = 0; r < 4; ++r) rowC[r] = rt * 16 + g * 4 + r;

    // ================= phase 1: q GEMM (Wq direct from global/L2) =================
    f4 aq0 = {0.f,0.f,0.f,0.f}, aq1 = {0.f,0.f,0.f,0.f};
    #pragma unroll
    for (int ks = 0; ks < 4; ++ks) {
        short8 A = ld8(sZ + rowA * 136 + ks * 32 + g * 8);
        const u16* wb = wsu + (ks * 4 + g) * 512;
        aq0 = MFMA(A, ld8(wb + col0 * 8), aq0);
        aq1 = MFMA(A, ld8(wb + col1 * 8), aq1);
    }
    // qv = 0.25 * (LN-corrected q); 1/sqrt(C)=0.25 folded here (q only feeds logits)
    float qv[2][4];
    {
        float GQ0 = sAux[col0], BQ0 = sAux[64 + col0];
        float GQ1 = sAux[col1], BQ1 = sAux[64 + col1];
        #pragma unroll
        for (int r = 0; r < 4; ++r) {
            float zr = sZr[rowC[r]], zm = sZrm[rowC[r]];
            qv[0][r] = 0.25f * fmaf(zr, aq0[r], fmaf(-zm, GQ0, BQ0));
            qv[1][r] = 0.25f * fmaf(zr, aq1[r], fmaf(-zm, GQ1, BQ1));
        }
    }

    // ================= phase 2: k GEMMs + logits =================
    // LN correction fused into k before the lane-dot:
    //   logit = sum_c qv * (tr*k - trm*GK + BK)   (tr,trm lane-uniform per 16-group)
    float lg[4][2][4];
    {
        const u16* wk = wsu + 8192;
        short8 Bk00 = ld8(wk + g * 512 + col0 * 8);
        short8 Bk01 = ld8(wk + g * 512 + col1 * 8);
        short8 Bk10 = ld8(wk + (4 + g) * 512 + col0 * 8);
        short8 Bk11 = ld8(wk + (4 + g) * 512 + col1 * 8);
        float GK0 = sAux[128 + col0], BK0 = sAux[192 + col0];
        float GK1 = sAux[128 + col1], BK1 = sAux[192 + col1];
        #pragma unroll
        for (int tt = 0; tt < 4; ++tt) {
            const u16* At = sT + tt * 2304 + rowA * 72;
            short8 A0 = ld8(At + g * 8);
            short8 A1 = ld8(At + 32 + g * 8);
            f4 k0 = {0.f,0.f,0.f,0.f}, k1 = {0.f,0.f,0.f,0.f};
            k0 = MFMA(A0, Bk00, k0); k1 = MFMA(A0, Bk01, k1);
            k0 = MFMA(A1, Bk10, k0); k1 = MFMA(A1, Bk11, k1);
            #pragma unroll
            for (int r = 0; r < 4; ++r) {
                float tr = sTr[tt * 32 + rowC[r]], tm = sTrm[tt * 32 + rowC[r]];
                float kc0 = fmaf(tr, k0[r], fmaf(-tm, GK0, BK0));
                float kc1 = fmaf(tr, k1[r], fmaf(-tm, GK1, BK1));
                lg[tt][0][r] = red16(qv[0][r] * kc0);
                lg[tt][1][r] = red16(qv[1][r] * kc1);
            }
        }
    }

    // ================= phase 3: softmax over T (in-lane) =================
    // exp -> mask -> renormalize is shift-invariant, so no -1e9 select needed;
    // logits are O(0.1) so no underflow. All-masked row: s=0 -> a=cb=cg=0.
    float ap[4][2][4], cb[2][4], cg[2][4];
    #pragma unroll
    for (int r = 0; r < 4; ++r) {
        float trA[4], tmA[4], pmA[4];
        #pragma unroll
        for (int tt = 0; tt < 4; ++tt) {
            trA[tt] = sTr[tt * 32 + rowC[r]];
            tmA[tt] = sTrm[tt * 32 + rowC[r]];
            pmA[tt] = sPm[tt * 32 + rowC[r]];
        }
        #pragma unroll
        for (int nn = 0; nn < 2; ++nn) {
            float l0 = lg[0][nn][r], l1 = lg[1][nn][r], l2 = lg[2][nn][r], l3 = lg[3][nn][r];
            float mx = fmaxf(fmaxf(l0, l1), fmaxf(l2, l3));
            float e0 = __expf(l0 - mx) * pmA[0];
            float e1 = __expf(l1 - mx) * pmA[1];
            float e2 = __expf(l2 - mx) * pmA[2];
            float e3 = __expf(l3 - mx) * pmA[3];
            float s = (e0 + e1) + (e2 + e3);
            float rr = __builtin_amdgcn_rcpf(fmaxf(s, 1e-20f));
            float a0 = e0 * rr, a1 = e1 * rr, a2 = e2 * rr, a3 = e3 * rr;
            cb[nn][r] = s * rr;   // == a0+a1+a2+a3 (1 if any unmasked, else 0)
            cg[nn][r] = a0 * tmA[0] + a1 * tmA[1] + a2 * tmA[2] + a3 * tmA[3];
            ap[0][nn][r] = a0 * trA[0]; ap[1][nn][r] = a1 * trA[1];
            ap[2][nn][r] = a2 * trA[2]; ap[3][nn][r] = a3 * trA[3];
        }
    }

    // ================= phase 4: v GEMMs + weighted accumulate =================
    float o0[4] = {0.f,0.f,0.f,0.f}, o1[4] = {0.f,0.f,0.f,0.f};
    {
        const u16* wv = wsu + 12288;
        short8 Bv00 = ld8(wv + g * 512 + col0 * 8);
        short8 Bv01 = ld8(wv + g * 512 + col1 * 8);
        short8 Bv10 = ld8(wv + (4 + g) * 512 + col0 * 8);
        short8 Bv11 = ld8(wv + (4 + g) * 512 + col1 * 8);
        #pragma unroll
        for (int tt = 0; tt < 4; ++tt) {
            const u16* At = sT + tt * 2304 + rowA * 72;
            short8 A0 = ld8(At + g * 8);
            short8 A1 = ld8(At + 32 + g * 8);
            f4 v0 = {0.f,0.f,0.f,0.f}, v1 = {0.f,0.f,0.f,0.f};
            v0 = MFMA(A0, Bv00, v0); v1 = MFMA(A0, Bv01, v1);
            v0 = MFMA(A1, Bv10, v0); v1 = MFMA(A1, Bv11, v1);
            #pragma unroll
            for (int r = 0; r < 4; ++r) {
                o0[r] = fmaf(ap[tt][0][r], v0[r], o0[r]);
                o1[r] = fmaf(ap[tt][1][r], v1[r], o1[r]);
            }
        }
        float GV0 = sAux[256 + col0], BV0 = sAux[320 + col0];
        float GV1 = sAux[256 + col1], BV1 = sAux[320 + col1];
        #pragma unroll
        for (int r = 0; r < 4; ++r) {
            o0[r] = fmaf(cb[0][r], BV0, fmaf(-cg[0][r], GV0, o0[r]));
            o1[r] = fmaf(cb[1][r], BV1, fmaf(-cg[1][r], GV1, o1[r]));
        }
    }
    __syncthreads();   // all waves past phase-1 sZ reads
    {   // write o (bf16, stride 72) into sZ region
        #pragma unroll
        for (int r = 0; r < 4; ++r) {
            sZ[rowC[r] * 72 + col0] = f2bf(o0[r]);
            sZ[rowC[r] * 72 + col1] = f2bf(o1[r]);
        }
    }
    __syncthreads();

    // ================= phase 5: out GEMM [32x64]@[64x128] (Wo direct) =================
    {
        const u16* wo = wsu + 16384;
        const int nb = (wave >> 1) * 4;      // 4 n-tiles per wave
        f4 c0 = {0.f,0.f,0.f,0.f}, c1 = {0.f,0.f,0.f,0.f};
        f4 c2 = {0.f,0.f,0.f,0.f}, c3 = {0.f,0.f,0.f,0.f};
        #pragma unroll
        for (int ks = 0; ks < 2; ++ks) {
            short8 A = ld8(sZ + rowA * 72 + ks * 32 + g * 8);
            const u16* wb = wo + (ks * 4 + g) * 1024;
            c0 = MFMA(A, ld8(wb + ((nb + 0) * 16 + l15) * 8), c0);
            c1 = MFMA(A, ld8(wb + ((nb + 1) * 16 + l15) * 8), c1);
            c2 = MFMA(A, ld8(wb + ((nb + 2) * 16 + l15) * 8), c2);
            c3 = MFMA(A, ld8(wb + ((nb + 3) * 16 + l15) * 8), c3);
        }
        #pragma unroll
        for (int r = 0; r < 4; ++r) {
            int row = p0 + rowC[r];
            float* op = out + (size_t)row * 128;
            op[(nb + 0) * 16 + l15] = c0[r] + sBo[(nb + 0) * 16 + l15];
            op[(nb + 1) * 16 + l15] = c1[r] + sBo[(nb + 1) * 16 + l15];
            op[(nb + 2) * 16 + l15] = c2[r] + sBo[(nb + 2) * 16 + l15];
            op[(nb + 3) * 16 + l15] = c3[r] + sBo[(nb + 3) * 16 + l15];
        }
    }
}

extern "C" void kernel_launch(void* const* d_in, const int* in_sizes, int n_in,
                              void* d_out, int out_size, void* d_ws, size_t ws_size,
                              hipStream_t stream) {
    const float* t   = (const float*)d_in[0];
    const float* z   = (const float*)d_in[1];
    const float* msk = (const float*)d_in[2];
    const float* zg  = (const float*)d_in[3];
    const float* zb  = (const float*)d_in[4];
    const float* tg  = (const float*)d_in[5];
    const float* tb  = (const float*)d_in[6];
    const float* Wq  = (const float*)d_in[7];
    const float* Wk  = (const float*)d_in[8];
    const float* Wv  = (const float*)d_in[9];
    const float* Wo  = (const float*)d_in[10];
    const float* bo  = (const float*)d_in[11];
    float* ws = (float*)d_ws;

    prep_w<<<96, 256, 0, stream>>>(Wq, Wk, Wv, Wo, zg, tg, ws);
    prep_aux<<<2, 256, 0, stream>>>(Wq, Wk, Wv, zg, zb, tg, tb, bo, ws);
    tpa_main<<<4608, 256, 0, stream>>>(t, z, msk, ws, (float*)d_out);
}

// Round 2
// 318.114 us; speedup vs baseline: 1.1506x; 1.1506x over previous
//
#include <hip/hip_runtime.h>

typedef unsigned int u32;
typedef unsigned short u16;
typedef __attribute__((ext_vector_type(8))) short short8;
typedef __attribute__((ext_vector_type(4))) float f4;

#define MFMA(a, b, c) __builtin_amdgcn_mfma_f32_16x16x32_bf16((a), (b), (c), 0, 0, 0)
#define LL 384
#define NPAIR 147456

// ---- helpers ----
__device__ __forceinline__ u16 f2bf(float f) {
    u32 u = __float_as_uint(f);
    u = (u + 0x7fffu + ((u >> 16) & 1u)) >> 16;
    return (u16)u;
}
__device__ __forceinline__ u32 pack2(float a, float b) {
    u32 ua = __float_as_uint(a); ua = (ua + 0x7fffu + ((ua >> 16) & 1u)) >> 16;
    u32 ub = __float_as_uint(b); ub = (ub + 0x7fffu + ((ub >> 16) & 1u)) >> 16;
    return ua | (ub << 16);
}
__device__ __forceinline__ short8 ld8(const u16* p) { return *reinterpret_cast<const short8*>(p); }

// 16-lane sum on the VALU pipe (DPP): quad_perm xor1/xor2 + row_ror:4/8.
template <int CTRL>
__device__ __forceinline__ float dpp_add(float v) {
    int t = __builtin_amdgcn_update_dpp(0, __float_as_int(v), CTRL, 0xf, 0xf, true);
    return v + __int_as_float(t);
}
__device__ __forceinline__ float red16(float v) {
    v = dpp_add<0xB1>(v);    // quad_perm [1,0,3,2]  (xor 1)
    v = dpp_add<0x4E>(v);    // quad_perm [2,3,0,1]  (xor 2)
    v = dpp_add<0x124>(v);   // row_ror:4
    v = dpp_add<0x128>(v);   // row_ror:8
    return v;
}

// ---- workspace layout ----
// u16 region: [0,8192) WqSW  [8192,12288) WkSW  [12288,16384) WvSW  [16384,24576) WoSW
// float region (float idx): [12288..] GQ BQ GK BK GV BV (64 each), bo at 12672 (128)
// swizzle: sw[(k>>3)*N*8 + n*8 + (k&7)] = W'[k][n]

__global__ void prep_w(const float* __restrict__ Wq, const float* __restrict__ Wk,
                       const float* __restrict__ Wv, const float* __restrict__ Wo,
                       const float* __restrict__ zg, const float* __restrict__ tg,
                       float* __restrict__ ws) {
    int idx = blockIdx.x * blockDim.x + threadIdx.x;
    u16* wsu = (u16*)ws;
    if (idx < 8192) {               // WqSW, N=64, K=128, fold zg
        int kb = idx >> 9, rem = idx & 511, n = rem >> 3, j = rem & 7, k = kb * 8 + j;
        wsu[idx] = f2bf(Wq[k * 64 + n] * zg[k]);
    } else if (idx < 12288) {       // WkSW, N=64, K=64, fold tg
        int e = idx - 8192;
        int kb = e >> 9, rem = e & 511, n = rem >> 3, j = rem & 7, k = kb * 8 + j;
        wsu[idx] = f2bf(Wk[k * 64 + n] * tg[k]);
    } else if (idx < 16384) {       // WvSW
        int e = idx - 12288;
        int kb = e >> 9, rem = e & 511, n = rem >> 3, j = rem & 7, k = kb * 8 + j;
        wsu[idx] = f2bf(Wv[k * 64 + n] * tg[k]);
    } else if (idx < 24576) {       // WoSW, N=128, K=64, no fold
        int e = idx - 16384;
        int kb = e >> 10, rem = e & 1023, n = rem >> 3, j = rem & 7, k = kb * 8 + j;
        wsu[idx] = f2bf(Wo[k * 128 + n]);
    }
}

__global__ void prep_aux(const float* __restrict__ Wq, const float* __restrict__ Wk,
                         const float* __restrict__ Wv, const float* __restrict__ zg,
                         const float* __restrict__ zb, const float* __restrict__ tg,
                         const float* __restrict__ tb, const float* __restrict__ bo,
                         float* __restrict__ ws) {
    int idx = blockIdx.x * blockDim.x + threadIdx.x;
    if (idx < 384) {
        int g = idx >> 6, hc = idx & 63;
        float acc = 0.f;
        if (g == 0)      { for (int d = 0; d < 128; ++d) acc += zg[d] * Wq[d*64+hc]; ws[12288+hc] = acc; }
        else if (g == 1) { for (int d = 0; d < 128; ++d) acc += zb[d] * Wq[d*64+hc]; ws[12352+hc] = acc; }
        else if (g == 2) { for (int d = 0; d < 64;  ++d) acc += tg[d] * Wk[d*64+hc]; ws[12416+hc] = acc; }
        else if (g == 3) { for (int d = 0; d < 64;  ++d) acc += tb[d] * Wk[d*64+hc]; ws[12480+hc] = acc; }
        else if (g == 4) { for (int d = 0; d < 64;  ++d) acc += tg[d] * Wv[d*64+hc]; ws[12544+hc] = acc; }
        else             { for (int d = 0; d < 64;  ++d) acc += tb[d] * Wv[d*64+hc]; ws[12608+hc] = acc; }
    } else if (idx < 512) {
        ws[12672 + idx - 384] = bo[idx - 384];
    }
}

// block = 256 threads (4 waves), M = 32 pairs/block, grid = 4608
// LDS ~30.5 KB; __launch_bounds__(256,4) -> 128-VGPR cap -> 4 blocks/CU,
// NO spills (the (256,5) variant forced <=64 VGPR -> 180 MB scratch traffic).
__global__ __launch_bounds__(256, 4) void tpa_main(
    const float* __restrict__ tmpl,   // [4][147456][64]
    const float* __restrict__ z,      // [147456][128]
    const float* __restrict__ mask,   // [4][384]
    const float* __restrict__ ws,
    float* __restrict__ out)          // [147456][128]
{
    __shared__ __align__(16) u16 sT[4 * 32 * 72];   // r*t bf16, stride 72 (LN scale folded)
    __shared__ __align__(16) u16 sZ[32 * 136];      // z bf16 stride 136; later o bf16 stride 72
    __shared__ float sZr[32], sZrm[32];
    __shared__ float sTrm[4 * 32];                  // r*mu per t-row (only LN term needed)
    __shared__ float sAux[384];                     // GQ BQ GK BK GV BV
    __shared__ float sBo[128];
    __shared__ float sPm[4 * 32];

    const int tid = threadIdx.x;
    const int p0 = blockIdx.x * 32;
    const u16* wsu = (const u16*)ws;

    // ================= phase 0: stage z/t tiles + aux =================
    if (tid < 128) {
        sAux[tid]       = ws[12288 + tid];
        sAux[128 + tid] = ws[12416 + tid];
        sAux[256 + tid] = ws[12544 + tid];
        sBo[tid]        = ws[12672 + tid];
        int tt = tid >> 5, rr = tid & 31;
        int p = p0 + rr, i = p / LL, j = p - i * LL;
        sPm[tt * 32 + rr] = mask[tt * LL + i] * mask[tt * LL + j];
    }
    {   // z tile: [32][128] f32, 8 threads/row
        int pp = tid >> 3, part = tid & 7;
        const float4* zg4 = (const float4*)(z + (size_t)(p0 + pp) * 128) + part * 4;
        float4 a0 = zg4[0], a1 = zg4[1], a2 = zg4[2], a3 = zg4[3];
        float s = a0.x+a0.y+a0.z+a0.w + a1.x+a1.y+a1.z+a1.w
                + a2.x+a2.y+a2.z+a2.w + a3.x+a3.y+a3.z+a3.w;
        float ss = a0.x*a0.x+a0.y*a0.y+a0.z*a0.z+a0.w*a0.w
                 + a1.x*a1.x+a1.y*a1.y+a1.z*a1.z+a1.w*a1.w
                 + a2.x*a2.x+a2.y*a2.y+a2.z*a2.z+a2.w*a2.w
                 + a3.x*a3.x+a3.y*a3.y+a3.z*a3.z+a3.w*a3.w;
        s += __shfl_xor(s, 1); ss += __shfl_xor(ss, 1);
        s += __shfl_xor(s, 2); ss += __shfl_xor(ss, 2);
        s += __shfl_xor(s, 4); ss += __shfl_xor(ss, 4);
        if (part == 0) {
            float mu = s * (1.f / 128.f);
            float var = fmaf(-mu, mu, ss * (1.f / 128.f));
            float r = rsqrtf(var + 1e-5f);
            sZr[pp] = r; sZrm[pp] = r * mu;
        }
        uint4 w0, w1;
        w0.x = pack2(a0.x, a0.y); w0.y = pack2(a0.z, a0.w);
        w0.z = pack2(a1.x, a1.y); w0.w = pack2(a1.z, a1.w);
        w1.x = pack2(a2.x, a2.y); w1.y = pack2(a2.z, a2.w);
        w1.z = pack2(a3.x, a3.y); w1.w = pack2(a3.z, a3.w);
        uint4* d = (uint4*)(sZ + pp * 136 + part * 16);
        d[0] = w0; d[1] = w1;
    }
    {   // t tiles: [4][32][64] f32, 2 threads/row; fold LN scale r into bf16 pack
        int tt = tid >> 6, pp = (tid >> 1) & 31, part = tid & 1;
        const float4* tg4 = (const float4*)(tmpl + ((size_t)tt * NPAIR + p0 + pp) * 64) + part * 8;
        float s = 0.f, ss = 0.f;
        float4 b[8];
        #pragma unroll
        for (int c = 0; c < 8; ++c) {
            b[c] = tg4[c];
            s  += b[c].x + b[c].y + b[c].z + b[c].w;
            ss += b[c].x*b[c].x + b[c].y*b[c].y + b[c].z*b[c].z + b[c].w*b[c].w;
        }
        s += __shfl_xor(s, 1); ss += __shfl_xor(ss, 1);
        float mu = s * (1.f / 64.f);
        float var = fmaf(-mu, mu, ss * (1.f / 64.f));
        float r = rsqrtf(var + 1e-5f);
        if (part == 0) sTrm[tt * 32 + pp] = r * mu;
        uint4 wbuf[4];
        #pragma unroll
        for (int c = 0; c < 4; ++c) {
            wbuf[c].x = pack2(b[2*c].x * r,   b[2*c].y * r);
            wbuf[c].y = pack2(b[2*c].z * r,   b[2*c].w * r);
            wbuf[c].z = pack2(b[2*c+1].x * r, b[2*c+1].y * r);
            wbuf[c].w = pack2(b[2*c+1].z * r, b[2*c+1].w * r);
        }
        uint4* d = (uint4*)(sT + tt * 2304 + pp * 72 + part * 32);
        d[0] = wbuf[0]; d[1] = wbuf[1]; d[2] = wbuf[2]; d[3] = wbuf[3];
    }
    __syncthreads();

    // wave partition: rt = row-tile (16 rows), nh = n-half (2 head-tiles)
    const int wave = tid >> 6, lane = tid & 63, g = lane >> 4, l15 = lane & 15;
    const int rt = wave & 1, nh = wave >> 1;
    const int rowA = rt * 16 + l15;
    const int col0 = (2 * nh) * 16 + l15, col1 = (2 * nh + 1) * 16 + l15;
    int rowC[4];
    #pragma unroll
    for (int r = 0; r < 4; ++r) rowC[r] = rt * 16 + g * 4 + r;

    // ================= phase 1: q GEMM (Wq direct from global/L2) =================
    f4 aq0 = {0.f,0.f,0.f,0.f}, aq1 = {0.f,0.f,0.f,0.f};
    #pragma unroll
    for (int ks = 0; ks < 4; ++ks) {
        short8 A = ld8(sZ + rowA * 136 + ks * 32 + g * 8);
        const u16* wb = wsu + (ks * 4 + g) * 512;
        aq0 = MFMA(A, ld8(wb + col0 * 8), aq0);
        aq1 = MFMA(A, ld8(wb + col1 * 8), aq1);
    }
    // qv = 0.25 * (LN-corrected q); 1/sqrt(C)=0.25 folded here (q only feeds logits)
    float qv[2][4];
    {
        float GQ0 = sAux[col0], BQ0 = sAux[64 + col0];
        float GQ1 = sAux[col1], BQ1 = sAux[64 + col1];
        #pragma unroll
        for (int r = 0; r < 4; ++r) {
            float zr = sZr[rowC[r]], zm = sZrm[rowC[r]];
            qv[0][r] = 0.25f * fmaf(zr, aq0[r], fmaf(-zm, GQ0, BQ0));
            qv[1][r] = 0.25f * fmaf(zr, aq1[r], fmaf(-zm, GQ1, BQ1));
        }
    }

    // ================= phase 2: k GEMMs + logits =================
    // sT already holds r*t, so MFMA gives r*(t @ tg*Wk); remaining LN terms:
    //   logit = sum_c qv * (k0 - trm*GK + BK)
    float lg[4][2][4];
    {
        const u16* wk = wsu + 8192;
        short8 Bk00 = ld8(wk + g * 512 + col0 * 8);
        short8 Bk01 = ld8(wk + g * 512 + col1 * 8);
        short8 Bk10 = ld8(wk + (4 + g) * 512 + col0 * 8);
        short8 Bk11 = ld8(wk + (4 + g) * 512 + col1 * 8);
        float GK0 = sAux[128 + col0], BK0 = sAux[192 + col0];
        float GK1 = sAux[128 + col1], BK1 = sAux[192 + col1];
        #pragma unroll
        for (int tt = 0; tt < 4; ++tt) {
            const u16* At = sT + tt * 2304 + rowA * 72;
            short8 A0 = ld8(At + g * 8);
            short8 A1 = ld8(At + 32 + g * 8);
            f4 k0 = {0.f,0.f,0.f,0.f}, k1 = {0.f,0.f,0.f,0.f};
            k0 = MFMA(A0, Bk00, k0); k1 = MFMA(A0, Bk01, k1);
            k0 = MFMA(A1, Bk10, k0); k1 = MFMA(A1, Bk11, k1);
            #pragma unroll
            for (int r = 0; r < 4; ++r) {
                float tm = sTrm[tt * 32 + rowC[r]];
                float kc0 = k0[r] + fmaf(-tm, GK0, BK0);
                float kc1 = k1[r] + fmaf(-tm, GK1, BK1);
                lg[tt][0][r] = red16(qv[0][r] * kc0);
                lg[tt][1][r] = red16(qv[1][r] * kc1);
            }
        }
    }

    // ================= phase 3: softmax over T (in-lane) =================
    // exp -> mask -> renormalize is shift-invariant, so no -1e9 select needed;
    // logits are O(0.1) so no underflow. All-masked row: s=0 -> a=cb=cg=0.
    float ap[4][2][4], cb[2][4], cg[2][4];
    #pragma unroll
    for (int r = 0; r < 4; ++r) {
        float tmA[4], pmA[4];
        #pragma unroll
        for (int tt = 0; tt < 4; ++tt) {
            tmA[tt] = sTrm[tt * 32 + rowC[r]];
            pmA[tt] = sPm[tt * 32 + rowC[r]];
        }
        #pragma unroll
        for (int nn = 0; nn < 2; ++nn) {
            float l0 = lg[0][nn][r], l1 = lg[1][nn][r], l2 = lg[2][nn][r], l3 = lg[3][nn][r];
            float mx = fmaxf(fmaxf(l0, l1), fmaxf(l2, l3));
            float e0 = __expf(l0 - mx) * pmA[0];
            float e1 = __expf(l1 - mx) * pmA[1];
            float e2 = __expf(l2 - mx) * pmA[2];
            float e3 = __expf(l3 - mx) * pmA[3];
            float s = (e0 + e1) + (e2 + e3);
            float rr = __builtin_amdgcn_rcpf(fmaxf(s, 1e-20f));
            float a0 = e0 * rr, a1 = e1 * rr, a2 = e2 * rr, a3 = e3 * rr;
            cb[nn][r] = s * rr;   // == a0+a1+a2+a3 (1 if any unmasked, else 0)
            cg[nn][r] = a0 * tmA[0] + a1 * tmA[1] + a2 * tmA[2] + a3 * tmA[3];
            ap[0][nn][r] = a0; ap[1][nn][r] = a1;
            ap[2][nn][r] = a2; ap[3][nn][r] = a3;
        }
    }

    // ================= phase 4: v GEMMs + weighted accumulate =================
    // sT holds r*t -> v0 = r*(t @ tg*Wv); o = sum_tt a*v0 - cg*GV + cb*BV
    float o0[4] = {0.f,0.f,0.f,0.f}, o1[4] = {0.f,0.f,0.f,0.f};
    {
        const u16* wv = wsu + 12288;
        short8 Bv00 = ld8(wv + g * 512 + col0 * 8);
        short8 Bv01 = ld8(wv + g * 512 + col1 * 8);
        short8 Bv10 = ld8(wv + (4 + g) * 512 + col0 * 8);
        short8 Bv11 = ld8(wv + (4 + g) * 512 + col1 * 8);
        #pragma unroll
        for (int tt = 0; tt < 4; ++tt) {
            const u16* At = sT + tt * 2304 + rowA * 72;
            short8 A0 = ld8(At + g * 8);
            short8 A1 = ld8(At + 32 + g * 8);
            f4 v0 = {0.f,0.f,0.f,0.f}, v1 = {0.f,0.f,0.f,0.f};
            v0 = MFMA(A0, Bv00, v0); v1 = MFMA(A0, Bv01, v1);
            v0 = MFMA(A1, Bv10, v0); v1 = MFMA(A1, Bv11, v1);
            #pragma unroll
            for (int r = 0; r < 4; ++r) {
                o0[r] = fmaf(ap[tt][0][r], v0[r], o0[r]);
                o1[r] = fmaf(ap[tt][1][r], v1[r], o1[r]);
            }
        }
        float GV0 = sAux[256 + col0], BV0 = sAux[320 + col0];
        float GV1 = sAux[256 + col1], BV1 = sAux[320 + col1];
        #pragma unroll
        for (int r = 0; r < 4; ++r) {
            o0[r] = fmaf(cb[0][r], BV0, fmaf(-cg[0][r], GV0, o0[r]));
            o1[r] = fmaf(cb[1][r], BV1, fmaf(-cg[1][r], GV1, o1[r]));
        }
    }
    __syncthreads();   // all waves past phase-1 sZ reads
    {   // write o (bf16, stride 72) into sZ region
        #pragma unroll
        for (int r = 0; r < 4; ++r) {
            sZ[rowC[r] * 72 + col0] = f2bf(o0[r]);
            sZ[rowC[r] * 72 + col1] = f2bf(o1[r]);
        }
    }
    __syncthreads();

    // ================= phase 5: out GEMM [32x64]@[64x128] (Wo direct) =================
    {
        const u16* wo = wsu + 16384;
        const int nb = (wave >> 1) * 4;      // 4 n-tiles per wave
        f4 c0 = {0.f,0.f,0.f,0.f}, c1 = {0.f,0.f,0.f,0.f};
        f4 c2 = {0.f,0.f,0.f,0.f}, c3 = {0.f,0.f,0.f,0.f};
        #pragma unroll
        for (int ks = 0; ks < 2; ++ks) {
            short8 A = ld8(sZ + rowA * 72 + ks * 32 + g * 8);
            const u16* wb = wo + (ks * 4 + g) * 1024;
            c0 = MFMA(A, ld8(wb + ((nb + 0) * 16 + l15) * 8), c0);
            c1 = MFMA(A, ld8(wb + ((nb + 1) * 16 + l15) * 8), c1);
            c2 = MFMA(A, ld8(wb + ((nb + 2) * 16 + l15) * 8), c2);
            c3 = MFMA(A, ld8(wb + ((nb + 3) * 16 + l15) * 8), c3);
        }
        #pragma unroll
        for (int r = 0; r < 4; ++r) {
            int row = p0 + rowC[r];
            float* op = out + (size_t)row * 128;
            op[(nb + 0) * 16 + l15] = c0[r] + sBo[(nb + 0) * 16 + l15];
            op[(nb + 1) * 16 + l15] = c1[r] + sBo[(nb + 1) * 16 + l15];
            op[(nb + 2) * 16 + l15] = c2[r] + sBo[(nb + 2) * 16 + l15];
            op[(nb + 3) * 16 + l15] = c3[r] + sBo[(nb + 3) * 16 + l15];
        }
    }
}

extern "C" void kernel_launch(void* const* d_in, const int* in_sizes, int n_in,
                              void* d_out, int out_size, void* d_ws, size_t ws_size,
                              hipStream_t stream) {
    const float* t   = (const float*)d_in[0];
    const float* z   = (const float*)d_in[1];
    const float* msk = (const float*)d_in[2];
    const float* zg  = (const float*)d_in[3];
    const float* zb  = (const float*)d_in[4];
    const float* tg  = (const float*)d_in[5];
    const float* tb  = (const float*)d_in[6];
    const float* Wq  = (const float*)d_in[7];
    const float* Wk  = (const float*)d_in[8];
    const float* Wv  = (const float*)d_in[9];
    const float* Wo  = (const float*)d_in[10];
    const float* bo  = (const float*)d_in[11];
    float* ws = (float*)d_ws;

    prep_w<<<96, 256, 0, stream>>>(Wq, Wk, Wv, Wo, zg, tg, ws);
    prep_aux<<<2, 256, 0, stream>>>(Wq, Wk, Wv, zg, zb, tg, tb, bo, ws);
    tpa_main<<<4608, 256, 0, stream>>>(t, z, msk, ws, (float*)d_out);
}